// Round 8
// baseline (172.909 us; speedup 1.0000x reference)
//
#include <hip/hip_runtime.h>
#include <math.h>

#define BB 8
#define NN 1024
#define MM 256
#define BETA 8
#define M1 16
#define NFEAT 64
#define HH 128
#define NTOT 1088   /* N + NGHOST */
#define F3 (NTOT*3) /* 3264 */
#define RMINf 0.5f
#define SPANf 5.5f
#define PIf 3.14159265358979323846f

#define OUT_EI 8
#define OUT_FORCE 8200          /* 8 + 8192 */
#define OUT_VIR 34312           /* 8200 + 8*1088*3 */

#define NG2 128                 /* scatter/bwd groups per batch (round-8 optimum) */
#define AT2 (NN/NG2)            /* 8 atoms per fused block */

#define MT 16                   /* atoms per MLP tile */
#define AS0 68                  /* xb stride (64+4), 16B-aligned rows */
#define AS1 132                 /* activation stride (128+4), 16B-aligned rows */

/* k_feat: 4 atoms per 256-thread block -> 2048 blocks + 640 weight-prep */
#define FEAT_BLKS 2048

/* workspace float offsets (fpart/virp slots retired this round) */
#define WS_S     0
#define WS_DF    (WS_S + 8192*64)
#define WS_STATP (WS_DF + 8192*64)
#define WS_WTB   (WS_STATP + 8192*2)     /* bf16 transposed weights: 81920 shorts */
#define WS_WB    (WS_WTB + 40960)        /* bf16 original weights: 81920 shorts */
#define WT0_OFF  0
#define WT1_OFF  16384
#define WT2_OFF  49152

typedef __attribute__((ext_vector_type(8))) short bf8;
typedef __attribute__((ext_vector_type(4))) float f4;

__device__ __forceinline__ float ftanh(float x) {
  const float e = __expf(2.0f*x);
  return 1.0f - 2.0f/(e + 1.0f);
}
__device__ __forceinline__ short f2bs(float f) {   /* fp32 -> bf16 RNE */
  unsigned u = __float_as_uint(f);
  return (short)((u + 0x7FFFu + ((u >> 16) & 1u)) >> 16);
}
__device__ __forceinline__ bf8 a_frag(const float* p) {  /* 8 consecutive fp32 -> bf16x8 */
  bf8 a;
  #pragma unroll
  for (int i = 0; i < 8; ++i) a[i] = f2bs(p[i]);
  return a;
}
__device__ __forceinline__ f4 splat4(float v) {
  f4 r; r[0] = v; r[1] = v; r[2] = v; r[3] = v; return r;
}
/* wave64 sum via DPP (VALU pipe, no LDS); total lands in lane 63 */
__device__ __forceinline__ float dpp_wave_sum(float x) {
  x += __int_as_float(__builtin_amdgcn_update_dpp(0, __float_as_int(x), 0x111, 0xf, 0xf, true));
  x += __int_as_float(__builtin_amdgcn_update_dpp(0, __float_as_int(x), 0x112, 0xf, 0xf, true));
  x += __int_as_float(__builtin_amdgcn_update_dpp(0, __float_as_int(x), 0x114, 0xf, 0xf, true));
  x += __int_as_float(__builtin_amdgcn_update_dpp(0, __float_as_int(x), 0x118, 0xf, 0xf, true));
  x += __int_as_float(__builtin_amdgcn_update_dpp(0, __float_as_int(x), 0x142, 0xf, 0xf, true));
  x += __int_as_float(__builtin_amdgcn_update_dpp(0, __float_as_int(x), 0x143, 0xf, 0xf, true));
  return x;
}

/* ---- features: wave-per-atom, DPP in-register reduction (round-7) ---- */
__global__ __launch_bounds__(256) void k_feat(
    const float* __restrict__ rvec, const int* __restrict__ tmap,
    const float* __restrict__ c_param, float* __restrict__ S_ws,
    float* __restrict__ statp,
    const float* __restrict__ W0, const float* __restrict__ W1,
    const float* __restrict__ W2,
    unsigned short* __restrict__ wtb, unsigned short* __restrict__ wb)
{
  const int tid = threadIdx.x;
  if (blockIdx.x >= FEAT_BLKS) {
    const int idx = (blockIdx.x - FEAT_BLKS)*256 + tid;  /* 0..163839 */
    if (idx < 81920) {
      unsigned short v;
      if (idx < 16384) {
        const int t = idx >> 13, rem = idx & 8191;
        const int j = rem >> 6, f = rem & 63;
        v = (unsigned short)f2bs(W0[t*8192 + f*128 + j]);
      } else if (idx < 49152) {
        const int i = idx - 16384;
        const int t = i >> 14, rem = i & 16383;
        const int j = rem >> 7, f = rem & 127;
        v = (unsigned short)f2bs(W1[t*16384 + f*128 + j]);
      } else {
        const int i = idx - 49152;
        const int t = i >> 14, rem = i & 16383;
        const int j = rem >> 7, f = rem & 127;
        v = (unsigned short)f2bs(W2[t*16384 + f*128 + j]);
      }
      wtb[idx] = v;
    } else {
      const int k = idx - 81920;
      float src;
      if (k < 16384) src = W0[k];
      else if (k < 49152) src = W1[k - 16384];
      else src = W2[k - 49152];
      wb[k] = (unsigned short)f2bs(src);
    }
    return;
  }
  __shared__ float cA[512];            /* full c_param: 2 types x 256 */
  __shared__ float Ubuf[4*64];         /* per-wave U[2][32] */
  __shared__ float Slds[4*64];         /* per-wave S[16][4] */
  cA[tid] = c_param[tid];
  cA[256 + tid] = c_param[256 + tid];
  __syncthreads();

  const int wave = tid >> 6, lane = tid & 63;
  const int bn = blockIdx.x*4 + wave;  /* < 8192 */
  const int n = bn & (NN-1);
  const int ti = tmap[n];
  const float* rb = rvec + (size_t)bn*MM*3;

  #pragma unroll
  for (int half = 0; half < 2; ++half) {
    float acc[32];
    #pragma unroll
    for (int c = 0; c < 32; ++c) acc[c] = 0.f;
    #pragma unroll
    for (int s = 0; s < 2; ++s) {
      const int m = half*128 + s*64 + lane;
      const float x = rb[3*m], y = rb[3*m+1], z = rb[3*m+2];
      const float r = sqrtf(x*x + y*y + z*z);
      const float ir = 1.0f/r;
      const float ux = x*ir, uy = y*ir, uz = z*ir;
      float u = 2.0f*(r - RMINf)/SPANf - 1.0f;
      u = fminf(fmaxf(u, -1.0f), 1.0f);
      const float fc = 0.5f*(__cosf(PIf*(r - RMINf)/SPANf) + 1.0f);
      float tm2 = 1.0f, tm1 = u;
      acc[0] += fc;  acc[1] += fc*ux;  acc[2] += fc*uy;  acc[3] += fc*uz;
      {
        const float ft = fc*u;
        acc[4] += ft; acc[5] += ft*ux; acc[6] += ft*uy; acc[7] += ft*uz;
      }
      #pragma unroll
      for (int k = 2; k < BETA; ++k) {
        const float tk = 2.0f*u*tm1 - tm2;
        const float ft = fc*tk;
        acc[k*4+0] += ft;
        acc[k*4+1] += ft*ux;
        acc[k*4+2] += ft*uy;
        acc[k*4+3] += ft*uz;
        tm2 = tm1; tm1 = tk;
      }
    }
    #pragma unroll
    for (int c = 0; c < 32; ++c) acc[c] = dpp_wave_sum(acc[c]);
    if (lane == 63) {
      float* Uw = &Ubuf[wave*64 + half*32];
      #pragma unroll
      for (int c = 0; c < 32; ++c) Uw[c] = acc[c];
    }
  }
  {
    const int p = lane >> 2, a = lane & 3;
    const float* Uw = &Ubuf[wave*64];
    const float* cw = &cA[ti*256];
    float s = 0.f;
    #pragma unroll
    for (int tj = 0; tj < 2; ++tj)
      #pragma unroll
      for (int k = 0; k < 8; ++k)
        s += cw[tj*128 + p*8 + k] * Uw[tj*32 + k*4 + a];
    s *= (1.0f/(float)MM);
    Slds[wave*64 + lane] = s;
    S_ws[(size_t)bn*64 + lane] = s;
  }
  {
    const int p = lane >> 2, q = lane & 3;
    const float* Sw = &Slds[wave*64];
    float f = 0.f;
    #pragma unroll
    for (int a = 0; a < 4; ++a) f += Sw[p*4+a]*Sw[q*4+a];
    float fs = f, fss = f*f;
    for (int o = 32; o > 0; o >>= 1) { fs += __shfl_down(fs, o); fss += __shfl_down(fss, o); }
    if (lane == 0) { statp[bn*2+0] = fs; statp[bn*2+1] = fss; }
  }
}

/* ---- MFMA bf16 MLP + fused Etot partial (this round) ---- */
__global__ __launch_bounds__(256) void k_mlp(
    const float* __restrict__ S_ws, const int* __restrict__ tmap,
    const float* __restrict__ statp,
    const unsigned short* __restrict__ wtb, const unsigned short* __restrict__ wb,
    const float* __restrict__ b0, const float* __restrict__ b1,
    const float* __restrict__ b2, const float* __restrict__ Wout,
    const float* __restrict__ bout,
    float* __restrict__ dfeat_ws, float* __restrict__ out)
{
  __shared__ float sl[MT*64];
  __shared__ float xb[MT*AS0];
  __shared__ float t0b[MT*AS1];
  __shared__ float h1b[MT*AS1];
  __shared__ float dzb[MT*AS1];
  __shared__ float es[MT];
  __shared__ float srd[8];
  __shared__ float muSd[2];
  const int tb = blockIdx.x;
  const int bn0 = tb*MT;
  const int tid = threadIdx.x;
  const int wave = tid >> 6, lane = tid & 63;
  const int quad = lane >> 4, nI = lane & 15;
  const int t = tmap[bn0 & (NN-1)];
  {
    const float4* src = (const float4*)(S_ws + (size_t)bn0*64);
    ((float4*)sl)[tid] = src[tid];
  }
  {
    float fs = 0.f, fss = 0.f;
    #pragma unroll 4
    for (int i = 0; i < 16; ++i) {
      const int e = i*256 + tid;
      const int b = e >> 9;
      const int n = t*512 + (e & 511);
      const float2 v = *(const float2*)&statp[((size_t)(b*NN + n))*2];
      fs += v.x; fss += v.y;
    }
    for (int o = 32; o > 0; o >>= 1) { fs += __shfl_down(fs, o); fss += __shfl_down(fss, o); }
    if ((tid & 63) == 0) { srd[(tid>>6)*2] = fs; srd[(tid>>6)*2+1] = fss; }
  }
  __syncthreads();
  if (tid == 0) {
    const float S1 = srd[0]+srd[2]+srd[4]+srd[6];
    const float S2 = srd[1]+srd[3]+srd[5]+srd[7];
    const float cnt = 512.0f * (float)BB * (float)NFEAT;
    const float mu = S1/cnt;
    const float var = (S2 - cnt*mu*mu)/(cnt - 1.0f);
    muSd[0] = mu; muSd[1] = sqrtf(fmaxf(var, 1e-20f));
  }
  __syncthreads();
  const float mu = muSd[0];
  const float inv_sd = 1.0f/muSd[1];
  #pragma unroll
  for (int i = 0; i < 4; ++i) {
    const int e = i*256 + tid;
    const int at = e >> 6, f = e & 63;
    const int p = f >> 2, q = f & 3;
    const float* Sr = &sl[at*64];
    float s = 0.f;
    #pragma unroll
    for (int a = 0; a < 4; ++a) s += Sr[p*4+a]*Sr[q*4+a];
    xb[at*AS0 + f] = (s - mu)*inv_sd;
  }
  __syncthreads();

  const int c0 = (wave*2+0)*16 + nI;
  const int c1 = (wave*2+1)*16 + nI;
  f4 acc0, acc1;

  /* L0 */
  acc0 = splat4(b0[t*HH + c0]);
  acc1 = splat4(b0[t*HH + c1]);
  {
    const unsigned short* B = wtb + WT0_OFF + t*8192;
    #pragma unroll
    for (int s = 0; s < 2; ++s) {
      const bf8 a  = a_frag(&xb[nI*AS0 + s*32 + quad*8]);
      const bf8 bA = *(const bf8*)&B[(size_t)c0*64 + s*32 + quad*8];
      const bf8 bB = *(const bf8*)&B[(size_t)c1*64 + s*32 + quad*8];
      acc0 = __builtin_amdgcn_mfma_f32_16x16x32_bf16(a, bA, acc0, 0, 0, 0);
      acc1 = __builtin_amdgcn_mfma_f32_16x16x32_bf16(a, bB, acc1, 0, 0, 0);
    }
  }
  #pragma unroll
  for (int r = 0; r < 4; ++r) {
    const int row = quad*4 + r;
    t0b[row*AS1 + c0] = ftanh(acc0[r]);
    t0b[row*AS1 + c1] = ftanh(acc1[r]);
  }
  __syncthreads();
  /* L1 */
  acc0 = splat4(b1[t*HH + c0]);
  acc1 = splat4(b1[t*HH + c1]);
  {
    const unsigned short* B = wtb + WT1_OFF + t*16384;
    #pragma unroll
    for (int s = 0; s < 4; ++s) {
      const bf8 a  = a_frag(&t0b[nI*AS1 + s*32 + quad*8]);
      const bf8 bA = *(const bf8*)&B[(size_t)c0*128 + s*32 + quad*8];
      const bf8 bB = *(const bf8*)&B[(size_t)c1*128 + s*32 + quad*8];
      acc0 = __builtin_amdgcn_mfma_f32_16x16x32_bf16(a, bA, acc0, 0, 0, 0);
      acc1 = __builtin_amdgcn_mfma_f32_16x16x32_bf16(a, bB, acc1, 0, 0, 0);
    }
  }
  #pragma unroll
  for (int r = 0; r < 4; ++r) {
    const int row = quad*4 + r;
    h1b[row*AS1 + c0] = ftanh(acc0[r]) + t0b[row*AS1 + c0];
    h1b[row*AS1 + c1] = ftanh(acc1[r]) + t0b[row*AS1 + c1];
  }
  __syncthreads();
  /* L2 */
  acc0 = splat4(b2[t*HH + c0]);
  acc1 = splat4(b2[t*HH + c1]);
  {
    const unsigned short* B = wtb + WT2_OFF + t*16384;
    #pragma unroll
    for (int s = 0; s < 4; ++s) {
      const bf8 a  = a_frag(&h1b[nI*AS1 + s*32 + quad*8]);
      const bf8 bA = *(const bf8*)&B[(size_t)c0*128 + s*32 + quad*8];
      const bf8 bB = *(const bf8*)&B[(size_t)c1*128 + s*32 + quad*8];
      acc0 = __builtin_amdgcn_mfma_f32_16x16x32_bf16(a, bA, acc0, 0, 0, 0);
      acc1 = __builtin_amdgcn_mfma_f32_16x16x32_bf16(a, bB, acc1, 0, 0, 0);
    }
  }
  #pragma unroll
  for (int r = 0; r < 4; ++r) {
    const int row = quad*4 + r;
    dzb[row*AS1 + c0] = acc0[r];
    dzb[row*AS1 + c1] = acc1[r];
  }
  __syncthreads();
  {
    const int at = tid >> 4, cb = (tid & 15)*8;
    const float* wop = Wout + t*HH;
    float ep = 0.f;
    #pragma unroll
    for (int j = 0; j < 8; ++j) {
      const int c = cb + j;
      const float z2 = dzb[at*AS1 + c];
      const float t2 = ftanh(z2);
      const float wo = wop[c];
      ep += (t2 + h1b[at*AS1 + c])*wo;
      dzb[at*AS1 + c] = wo*(1.0f - t2*t2);
    }
    ep += __shfl_down(ep, 8, 16);
    ep += __shfl_down(ep, 4, 16);
    ep += __shfl_down(ep, 2, 16);
    ep += __shfl_down(ep, 1, 16);
    if ((tid & 15) == 0) es[at] = ep;
  }
  __syncthreads();
  if (tid < MT) out[OUT_EI + bn0 + tid] = es[tid] + bout[t];
  /* fused Etot partial: one atomic per block into out[b] (out zeroed by memset) */
  if (tid == 0) {
    float s = 0.f;
    #pragma unroll
    for (int i = 0; i < MT; ++i) s += es[i];
    atomicAdd(&out[bn0 >> 10], s + (float)MT*bout[t]);
  }

  /* BGEMM1: dh1 = wo + dz2 @ W2^T */
  {
    const float* wop = Wout + t*HH;
    acc0 = splat4(wop[c0]);
    acc1 = splat4(wop[c1]);
    const unsigned short* B = wb + WT2_OFF + t*16384;
    #pragma unroll
    for (int s = 0; s < 4; ++s) {
      const bf8 a  = a_frag(&dzb[nI*AS1 + s*32 + quad*8]);
      const bf8 bA = *(const bf8*)&B[(size_t)c0*128 + s*32 + quad*8];
      const bf8 bB = *(const bf8*)&B[(size_t)c1*128 + s*32 + quad*8];
      acc0 = __builtin_amdgcn_mfma_f32_16x16x32_bf16(a, bA, acc0, 0, 0, 0);
      acc1 = __builtin_amdgcn_mfma_f32_16x16x32_bf16(a, bB, acc1, 0, 0, 0);
    }
  }
  __syncthreads();
  float dh10[4], dh11[4];
  #pragma unroll
  for (int r = 0; r < 4; ++r) {
    const int row = quad*4 + r;
    dh10[r] = acc0[r]; dh11[r] = acc1[r];
    const float t1a = h1b[row*AS1 + c0] - t0b[row*AS1 + c0];
    const float t1b = h1b[row*AS1 + c1] - t0b[row*AS1 + c1];
    dzb[row*AS1 + c0] = acc0[r]*(1.0f - t1a*t1a);
    dzb[row*AS1 + c1] = acc1[r]*(1.0f - t1b*t1b);
  }
  __syncthreads();
  /* BGEMM2: dh0 = dh1 + dz1 @ W1^T */
  acc0[0]=dh10[0]; acc0[1]=dh10[1]; acc0[2]=dh10[2]; acc0[3]=dh10[3];
  acc1[0]=dh11[0]; acc1[1]=dh11[1]; acc1[2]=dh11[2]; acc1[3]=dh11[3];
  {
    const unsigned short* B = wb + WT1_OFF + t*16384;
    #pragma unroll
    for (int s = 0; s < 4; ++s) {
      const bf8 a  = a_frag(&dzb[nI*AS1 + s*32 + quad*8]);
      const bf8 bA = *(const bf8*)&B[(size_t)c0*128 + s*32 + quad*8];
      const bf8 bB = *(const bf8*)&B[(size_t)c1*128 + s*32 + quad*8];
      acc0 = __builtin_amdgcn_mfma_f32_16x16x32_bf16(a, bA, acc0, 0, 0, 0);
      acc1 = __builtin_amdgcn_mfma_f32_16x16x32_bf16(a, bB, acc1, 0, 0, 0);
    }
  }
  __syncthreads();
  #pragma unroll
  for (int r = 0; r < 4; ++r) {
    const int row = quad*4 + r;
    const float ta = t0b[row*AS1 + c0], tb = t0b[row*AS1 + c1];
    dzb[row*AS1 + c0] = acc0[r]*(1.0f - ta*ta);
    dzb[row*AS1 + c1] = acc1[r]*(1.0f - tb*tb);
  }
  __syncthreads();
  /* BGEMM3: dx = dz0 @ W0^T */
  {
    const int cx = wave*16 + nI;
    acc0 = splat4(0.f);
    const unsigned short* B = wb + WT0_OFF + t*8192;
    #pragma unroll
    for (int s = 0; s < 4; ++s) {
      const bf8 a  = a_frag(&dzb[nI*AS1 + s*32 + quad*8]);
      const bf8 bA = *(const bf8*)&B[(size_t)cx*128 + s*32 + quad*8];
      acc0 = __builtin_amdgcn_mfma_f32_16x16x32_bf16(a, bA, acc0, 0, 0, 0);
    }
    #pragma unroll
    for (int r = 0; r < 4; ++r)
      dfeat_ws[(size_t)(bn0 + quad*4 + r)*64 + cx] = acc0[r]*inv_sd;
  }
}

/* ---- fused backward pair + scatter + DIRECT global-atomic output ----
   Round-0 body (48.0 us, traffic-clean). This round: the fpart_ws spill
   (13.4 MB wr) + k_reduce (13.4 MB rd + 408 blocks + launch) are replaced
   by direct atomicAdd into out[OUT_FORCE] (104 KB hot region -> L2-resident
   atomics) issued into the kernel's idle VMEM pipe (HBM was 8%). Virial
   likewise: 9 atomics/block. out is zeroed by hipMemsetAsync up front. */
__global__ __launch_bounds__(256, 4) void k_bwdsc(
    const float* __restrict__ rvec, const int* __restrict__ nlist,
    const int* __restrict__ tmap, const float* __restrict__ c_param,
    const float* __restrict__ S_ws, const float* __restrict__ dfeat_ws,
    float* __restrict__ out)
{
  __shared__ float c_lds[256];
  __shared__ float Sb[AT2*64];
  __shared__ float Db[AT2*64];
  __shared__ float dSb[AT2*64];
  __shared__ float Eb[AT2*64];
  __shared__ float fpart[F3];
  __shared__ float wredc[AT2*4*3];
  __shared__ float vred[4*9];
  const int blk = blockIdx.x;          /* b*NG2 + g */
  const int b = blk >> 7;
  const int g = blk & (NG2-1);
  const int n0 = g*AT2;
  const int tid = threadIdx.x;
  const int ti = tmap[n0];             /* type uniform across group (8|512) */
  c_lds[tid] = c_param[ti*256 + tid];
  if (tid < 128) {
    const float4* s4 = (const float4*)(S_ws + ((size_t)b*NN + n0)*64);
    const float4* d4 = (const float4*)(dfeat_ws + ((size_t)b*NN + n0)*64);
    ((float4*)Sb)[tid] = s4[tid];
    ((float4*)Db)[tid] = d4[tid];
  }
  {
    const float4 z4 = {0.f, 0.f, 0.f, 0.f};
    for (int i = tid; i < F3/4; i += 256) ((float4*)fpart)[i] = z4;
  }
  __syncthreads();
  #pragma unroll
  for (int it = 0; it < 2; ++it) {
    const int idx = it*256 + tid;
    const int at = idx >> 6, f = idx & 63;
    const int i = f >> 2, a = f & 3;
    const float* Sr = &Sb[at*64];
    const float* Dr = &Db[at*64];
    float v = 0.f;
    #pragma unroll
    for (int q = 0; q < 4; ++q) v += Dr[i*4+q]*Sr[q*4+a];
    if (i < 4)
      for (int p = 0; p < 16; ++p) v += Dr[p*4+i]*Sr[p*4+a];
    dSb[idx] = v;
  }
  __syncthreads();
  #pragma unroll
  for (int it = 0; it < 2; ++it) {
    const int idx = it*256 + tid;
    const int at = idx >> 6, rem = idx & 63;
    const int tj = rem >> 5, a = (rem >> 3) & 3, k = rem & 7;
    float e = 0.f;
    #pragma unroll
    for (int p = 0; p < 16; ++p) e += dSb[at*64 + p*4 + a]*c_lds[tj*128 + p*8 + k];
    Eb[idx] = e;
  }
  __syncthreads();

  float vir[9];
  #pragma unroll
  for (int i = 0; i < 9; ++i) vir[i] = 0.f;
  const int wave = tid >> 6, lane = tid & 63;
  const int tjm = tid >> 7;
  const float dudr = 2.0f/SPANf;
  const float invM = 1.0f/(float)MM;

  const size_t rowbase = ((size_t)b*NN + n0)*MM;
  float px0, py0, pz0, px1, py1, pz1; int pnl0, pnl1;
  {
    const float* rp0 = rvec + (rowbase + tid)*3;
    const float* rp1 = rvec + (rowbase + MM + tid)*3;
    px0 = rp0[0]; py0 = rp0[1]; pz0 = rp0[2]; pnl0 = nlist[rowbase + tid];
    px1 = rp1[0]; py1 = rp1[1]; pz1 = rp1[2]; pnl1 = nlist[rowbase + MM + tid];
  }
  for (int a0 = 0; a0 < AT2; a0 += 2) {
    const float x0 = px0, y0 = py0, z0 = pz0; const int nl0 = pnl0;
    const float x1 = px1, y1 = py1, z1 = pz1; const int nl1 = pnl1;
    if (a0 + 2 < AT2) {
      const float* rp0 = rvec + (rowbase + (size_t)(a0+2)*MM + tid)*3;
      const float* rp1 = rvec + (rowbase + (size_t)(a0+3)*MM + tid)*3;
      px0 = rp0[0]; py0 = rp0[1]; pz0 = rp0[2];
      pnl0 = nlist[rowbase + (size_t)(a0+2)*MM + tid];
      px1 = rp1[0]; py1 = rp1[1]; pz1 = rp1[2];
      pnl1 = nlist[rowbase + (size_t)(a0+3)*MM + tid];
    }
    float Er0[32], Er1[32];
    {
      const float4* p0 = (const float4*)&Eb[a0*64 + tjm*32];
      const float4* p1 = (const float4*)&Eb[(a0+1)*64 + tjm*32];
      #pragma unroll
      for (int q = 0; q < 8; ++q) {
        const float4 v0 = p0[q], v1 = p1[q];
        Er0[q*4+0]=v0.x; Er0[q*4+1]=v0.y; Er0[q*4+2]=v0.z; Er0[q*4+3]=v0.w;
        Er1[q*4+0]=v1.x; Er1[q*4+1]=v1.y; Er1[q*4+2]=v1.z; Er1[q*4+3]=v1.w;
      }
    }
    const float r_0 = sqrtf(x0*x0 + y0*y0 + z0*z0);
    const float r_1 = sqrtf(x1*x1 + y1*y1 + z1*z1);
    const float ir0 = 1.0f/r_0, ir1 = 1.0f/r_1;
    const float ux0 = x0*ir0, uy0 = y0*ir0, uz0 = z0*ir0;
    const float ux1 = x1*ir1, uy1 = y1*ir1, uz1 = z1*ir1;
    float u0 = 2.0f*(r_0 - RMINf)/SPANf - 1.0f;
    float u1 = 2.0f*(r_1 - RMINf)/SPANf - 1.0f;
    u0 = fminf(fmaxf(u0, -1.0f), 1.0f);
    u1 = fminf(fmaxf(u1, -1.0f), 1.0f);
    float s0a, c0a, s1a, c1a;
    __sincosf(PIf*(r_0 - RMINf)/SPANf, &s0a, &c0a);
    __sincosf(PIf*(r_1 - RMINf)/SPANf, &s1a, &c1a);
    const float fc0 = 0.5f*(c0a + 1.0f), dfc0 = -0.5f*(PIf/SPANf)*s0a;
    const float fc1 = 0.5f*(c1a + 1.0f), dfc1 = -0.5f*(PIf/SPANf)*s1a;
    float ta0[4], tda0[4], ta1[4], tda1[4];
    #pragma unroll
    for (int aa = 0; aa < 4; ++aa) {
      ta0[aa]  = Er0[aa*8] + Er0[aa*8+1]*u0;
      tda0[aa] = Er0[aa*8+1];
      ta1[aa]  = Er1[aa*8] + Er1[aa*8+1]*u1;
      tda1[aa] = Er1[aa*8+1];
    }
    float t0m2 = 1.f, t0m1 = u0, d0m2 = 0.f, d0m1 = 1.f;
    float t1m2 = 1.f, t1m1 = u1, d1m2 = 0.f, d1m1 = 1.f;
    #pragma unroll
    for (int k = 2; k < BETA; ++k) {
      const float tk0 = 2.f*u0*t0m1 - t0m2;
      const float dk0 = 2.f*t0m1 + 2.f*u0*d0m1 - d0m2;
      const float tk1 = 2.f*u1*t1m1 - t1m2;
      const float dk1 = 2.f*t1m1 + 2.f*u1*d1m1 - d1m2;
      #pragma unroll
      for (int aa = 0; aa < 4; ++aa) {
        ta0[aa]  += Er0[aa*8+k]*tk0;
        tda0[aa] += Er0[aa*8+k]*dk0;
        ta1[aa]  += Er1[aa*8+k]*tk1;
        tda1[aa] += Er1[aa*8+k]*dk1;
      }
      t0m2 = t0m1; t0m1 = tk0; d0m2 = d0m1; d0m1 = dk0;
      t1m2 = t1m1; t1m1 = tk1; d1m2 = d1m1; d1m1 = dk1;
    }
    float A0 = dfc0*(ta0[0] + ux0*ta0[1] + uy0*ta0[2] + uz0*ta0[3])
             + fc0*dudr*(tda0[0] + ux0*tda0[1] + uy0*tda0[2] + uz0*tda0[3]);
    float A1 = dfc1*(ta1[0] + ux1*ta1[1] + uy1*ta1[2] + uz1*ta1[3])
             + fc1*dudr*(tda1[0] + ux1*tda1[1] + uy1*tda1[2] + uz1*tda1[3]);
    float q10 = fc0*ta0[1], q20 = fc0*ta0[2], q30 = fc0*ta0[3];
    float q11 = fc1*ta1[1], q21 = fc1*ta1[2], q31 = fc1*ta1[3];
    A0 *= invM; q10 *= invM; q20 *= invM; q30 *= invM;
    A1 *= invM; q11 *= invM; q21 *= invM; q31 *= invM;
    const float qu0 = q10*ux0 + q20*uy0 + q30*uz0;
    const float qu1 = q11*ux1 + q21*uy1 + q31*uz1;
    const float d00 = A0*ux0 + (q10 - qu0*ux0)*ir0;
    const float d01 = A0*uy0 + (q20 - qu0*uy0)*ir0;
    const float d02 = A0*uz0 + (q30 - qu0*uz0)*ir0;
    const float d10 = A1*ux1 + (q11 - qu1*ux1)*ir1;
    const float d11 = A1*uy1 + (q21 - qu1*uy1)*ir1;
    const float d12 = A1*uz1 + (q31 - qu1*uz1)*ir1;
    if (nl0 > 0) {
      const int j = nl0 - 1;
      atomicAdd(&fpart[j*3+0], -d00);
      atomicAdd(&fpart[j*3+1], -d01);
      atomicAdd(&fpart[j*3+2], -d02);
    }
    if (nl1 > 0) {
      const int j = nl1 - 1;
      atomicAdd(&fpart[j*3+0], -d10);
      atomicAdd(&fpart[j*3+1], -d11);
      atomicAdd(&fpart[j*3+2], -d12);
    }
    vir[0] -= x0*d00 + x1*d10; vir[1] -= x0*d01 + x1*d11; vir[2] -= x0*d02 + x1*d12;
    vir[3] -= y0*d00 + y1*d10; vir[4] -= y0*d01 + y1*d11; vir[5] -= y0*d02 + y1*d12;
    vir[6] -= z0*d00 + z1*d10; vir[7] -= z0*d01 + z1*d11; vir[8] -= z0*d02 + z1*d12;
    const float r00 = dpp_wave_sum(d00), r01 = dpp_wave_sum(d01), r02 = dpp_wave_sum(d02);
    const float r10 = dpp_wave_sum(d10), r11 = dpp_wave_sum(d11), r12 = dpp_wave_sum(d12);
    if (lane == 63) {
      wredc[(a0*4 + wave)*3 + 0] = r00;
      wredc[(a0*4 + wave)*3 + 1] = r01;
      wredc[(a0*4 + wave)*3 + 2] = r02;
      wredc[((a0+1)*4 + wave)*3 + 0] = r10;
      wredc[((a0+1)*4 + wave)*3 + 1] = r11;
      wredc[((a0+1)*4 + wave)*3 + 2] = r12;
    }
  }
  #pragma unroll
  for (int i = 0; i < 9; ++i) {
    const float v = dpp_wave_sum(vir[i]);
    if (lane == 63) vred[wave*9 + i] = v;
  }
  __syncthreads();
  if (tid < AT2*3) {
    const int at = tid/3, c = tid - at*3;
    const float v = wredc[(at*4+0)*3+c] + wredc[(at*4+1)*3+c]
                  + wredc[(at*4+2)*3+c] + wredc[(at*4+3)*3+c];
    atomicAdd(&fpart[(n0+at)*3 + c], v);
  }
  if (tid >= 64 && tid < 73) {
    const int i = tid - 64;
    atomicAdd(&out[OUT_VIR + b*9 + i],
              vred[i] + vred[9+i] + vred[18+i] + vred[27+i]);
  }
  __syncthreads();
  {
    float* dst = out + OUT_FORCE + (size_t)b*F3;
    for (int i = tid; i < F3; i += 256)
      atomicAdd(&dst[i], fpart[i]);
  }
}

extern "C" void kernel_launch(void* const* d_in, const int* in_sizes, int n_in,
                              void* d_out, int out_size, void* d_ws, size_t ws_size,
                              hipStream_t stream)
{
  const int*   nlist = (const int*)d_in[0];
  const int*   tmap  = (const int*)d_in[1];
  const float* rvec  = (const float*)d_in[2];
  const float* cpar  = (const float*)d_in[3];
  const float* W0 = (const float*)d_in[4];
  const float* b0 = (const float*)d_in[5];
  const float* W1 = (const float*)d_in[6];
  const float* b1 = (const float*)d_in[7];
  const float* W2 = (const float*)d_in[8];
  const float* b2 = (const float*)d_in[9];
  const float* Wout = (const float*)d_in[10];
  const float* bout = (const float*)d_in[11];
  float* out = (float*)d_out;
  float* ws = (float*)d_ws;
  float* S_ws   = ws + WS_S;
  float* df_ws  = ws + WS_DF;
  float* statp  = ws + WS_STATP;
  unsigned short* wtb = (unsigned short*)(ws + WS_WTB);
  unsigned short* wb  = (unsigned short*)(ws + WS_WB);

  /* zero output: Etot/Force/Virial are now atomic-accumulated */
  hipMemsetAsync(d_out, 0, (size_t)out_size, stream);

  k_feat <<<FEAT_BLKS + 640, 256, 0, stream>>>(rvec, tmap, cpar, S_ws, statp,
                                               W0, W1, W2, wtb, wb);
  k_mlp  <<<(BB*NN)/MT, 256, 0, stream>>>(S_ws, tmap, statp, wtb, wb,
                                          b0, b1, b2, Wout, bout, df_ws, out);
  k_bwdsc<<<BB*NG2, 256, 0, stream>>>(rvec, nlist, tmap, cpar, S_ws, df_ws,
                                      out);
}

// Round 9
// 167.703 us; speedup vs baseline: 1.0310x; 1.0310x over previous
//
#include <hip/hip_runtime.h>
#include <math.h>

#define BB 8
#define NN 1024
#define MM 256
#define BETA 8
#define M1 16
#define NFEAT 64
#define HH 128
#define NTOT 1088   /* N + NGHOST */
#define F3 (NTOT*3) /* 3264 */
#define RMINf 0.5f
#define SPANf 5.5f
#define PIf 3.14159265358979323846f

#define OUT_EI 8
#define OUT_FORCE 8200          /* 8 + 8192 */
#define OUT_VIR 34312           /* 8200 + 8*1088*3 */

#define MT 16                   /* atoms per fused tile */
#define FUSE_BLKS ((BB*NN)/MT)  /* 512 */
#define AS0 68                  /* xb stride (64+4) */
#define AS1 132                 /* activation stride (128+4) */

/* k_feat: 4 atoms per 256-thread block -> 2048 blocks + 640 weight-prep */
#define FEAT_BLKS 2048

/* workspace float offsets (df_ws retired: dfeat stays in LDS now) */
#define WS_S     0
#define WS_STATP (WS_S + 8192*64)
#define WS_WTB   (WS_STATP + 8192*2)     /* bf16 transposed weights: 81920 shorts */
#define WS_WB    (WS_WTB + 40960)        /* bf16 original weights: 81920 shorts */
#define WT0_OFF  0
#define WT1_OFF  16384
#define WT2_OFF  49152

/* ---- fused-kernel shared memory layout (floats). Overlays:
   fpart[0,3264) over sl+xb+t0b after Eb is built;
   dSb(1024) over t0b; Eb(1024) over h1b; Db/dfeat(1024) over dzb. ---- */
#define SL_O  0        /* 1024: S 16x64 */
#define XB_O  1024     /* 1088: xb 16x68 */
#define T0_O  2112     /* 2112: t0b 16x132 */
#define H1_O  4224     /* 2112: h1b 16x132 */
#define DZ_O  6336     /* 2112: dzb 16x132 */
#define CL_O  8448     /* 256: c_param row */
#define ES_O  8704     /* 16 */
#define SRD_O 8720     /* 8 */
#define MU_O  8728     /* 2 */
#define WR_O  8730     /* 192: wredc 16x4x3 */
#define VR_O  8922     /* 36: vred 4x9 */
#define SM_TOT 8958    /* ~35.8 KB */

typedef __attribute__((ext_vector_type(8))) short bf8;
typedef __attribute__((ext_vector_type(4))) float f4;

__device__ __forceinline__ float ftanh(float x) {
  const float e = __expf(2.0f*x);
  return 1.0f - 2.0f/(e + 1.0f);
}
__device__ __forceinline__ short f2bs(float f) {   /* fp32 -> bf16 RNE */
  unsigned u = __float_as_uint(f);
  return (short)((u + 0x7FFFu + ((u >> 16) & 1u)) >> 16);
}
__device__ __forceinline__ bf8 a_frag(const float* p) {  /* 8 consecutive fp32 -> bf16x8 */
  bf8 a;
  #pragma unroll
  for (int i = 0; i < 8; ++i) a[i] = f2bs(p[i]);
  return a;
}
__device__ __forceinline__ f4 splat4(float v) {
  f4 r; r[0] = v; r[1] = v; r[2] = v; r[3] = v; return r;
}
/* wave64 sum via DPP (VALU pipe, no LDS); total lands in lane 63 */
__device__ __forceinline__ float dpp_wave_sum(float x) {
  x += __int_as_float(__builtin_amdgcn_update_dpp(0, __float_as_int(x), 0x111, 0xf, 0xf, true));
  x += __int_as_float(__builtin_amdgcn_update_dpp(0, __float_as_int(x), 0x112, 0xf, 0xf, true));
  x += __int_as_float(__builtin_amdgcn_update_dpp(0, __float_as_int(x), 0x114, 0xf, 0xf, true));
  x += __int_as_float(__builtin_amdgcn_update_dpp(0, __float_as_int(x), 0x118, 0xf, 0xf, true));
  x += __int_as_float(__builtin_amdgcn_update_dpp(0, __float_as_int(x), 0x142, 0xf, 0xf, true));
  x += __int_as_float(__builtin_amdgcn_update_dpp(0, __float_as_int(x), 0x143, 0xf, 0xf, true));
  return x;
}

/* ---- features: wave-per-atom, DPP in-register reduction (round-7) ---- */
__global__ __launch_bounds__(256) void k_feat(
    const float* __restrict__ rvec, const int* __restrict__ tmap,
    const float* __restrict__ c_param, float* __restrict__ S_ws,
    float* __restrict__ statp,
    const float* __restrict__ W0, const float* __restrict__ W1,
    const float* __restrict__ W2,
    unsigned short* __restrict__ wtb, unsigned short* __restrict__ wb)
{
  const int tid = threadIdx.x;
  if (blockIdx.x >= FEAT_BLKS) {
    const int idx = (blockIdx.x - FEAT_BLKS)*256 + tid;  /* 0..163839 */
    if (idx < 81920) {
      unsigned short v;
      if (idx < 16384) {
        const int t = idx >> 13, rem = idx & 8191;
        const int j = rem >> 6, f = rem & 63;
        v = (unsigned short)f2bs(W0[t*8192 + f*128 + j]);
      } else if (idx < 49152) {
        const int i = idx - 16384;
        const int t = i >> 14, rem = i & 16383;
        const int j = rem >> 7, f = rem & 127;
        v = (unsigned short)f2bs(W1[t*16384 + f*128 + j]);
      } else {
        const int i = idx - 49152;
        const int t = i >> 14, rem = i & 16383;
        const int j = rem >> 7, f = rem & 127;
        v = (unsigned short)f2bs(W2[t*16384 + f*128 + j]);
      }
      wtb[idx] = v;
    } else {
      const int k = idx - 81920;
      float src;
      if (k < 16384) src = W0[k];
      else if (k < 49152) src = W1[k - 16384];
      else src = W2[k - 49152];
      wb[k] = (unsigned short)f2bs(src);
    }
    return;
  }
  __shared__ float cA[512];            /* full c_param: 2 types x 256 */
  __shared__ float Ubuf[4*64];         /* per-wave U[2][32] */
  __shared__ float Slds[4*64];         /* per-wave S[16][4] */
  cA[tid] = c_param[tid];
  cA[256 + tid] = c_param[256 + tid];
  __syncthreads();

  const int wave = tid >> 6, lane = tid & 63;
  const int bn = blockIdx.x*4 + wave;  /* < 8192 */
  const int n = bn & (NN-1);
  const int ti = tmap[n];
  const float* rb = rvec + (size_t)bn*MM*3;

  #pragma unroll
  for (int half = 0; half < 2; ++half) {
    float acc[32];
    #pragma unroll
    for (int c = 0; c < 32; ++c) acc[c] = 0.f;
    #pragma unroll
    for (int s = 0; s < 2; ++s) {
      const int m = half*128 + s*64 + lane;
      const float x = rb[3*m], y = rb[3*m+1], z = rb[3*m+2];
      const float r = sqrtf(x*x + y*y + z*z);
      const float ir = 1.0f/r;
      const float ux = x*ir, uy = y*ir, uz = z*ir;
      float u = 2.0f*(r - RMINf)/SPANf - 1.0f;
      u = fminf(fmaxf(u, -1.0f), 1.0f);
      const float fc = 0.5f*(__cosf(PIf*(r - RMINf)/SPANf) + 1.0f);
      float tm2 = 1.0f, tm1 = u;
      acc[0] += fc;  acc[1] += fc*ux;  acc[2] += fc*uy;  acc[3] += fc*uz;
      {
        const float ft = fc*u;
        acc[4] += ft; acc[5] += ft*ux; acc[6] += ft*uy; acc[7] += ft*uz;
      }
      #pragma unroll
      for (int k = 2; k < BETA; ++k) {
        const float tk = 2.0f*u*tm1 - tm2;
        const float ft = fc*tk;
        acc[k*4+0] += ft;
        acc[k*4+1] += ft*ux;
        acc[k*4+2] += ft*uy;
        acc[k*4+3] += ft*uz;
        tm2 = tm1; tm1 = tk;
      }
    }
    #pragma unroll
    for (int c = 0; c < 32; ++c) acc[c] = dpp_wave_sum(acc[c]);
    if (lane == 63) {
      float* Uw = &Ubuf[wave*64 + half*32];
      #pragma unroll
      for (int c = 0; c < 32; ++c) Uw[c] = acc[c];
    }
  }
  {
    const int p = lane >> 2, a = lane & 3;
    const float* Uw = &Ubuf[wave*64];
    const float* cw = &cA[ti*256];
    float s = 0.f;
    #pragma unroll
    for (int tj = 0; tj < 2; ++tj)
      #pragma unroll
      for (int k = 0; k < 8; ++k)
        s += cw[tj*128 + p*8 + k] * Uw[tj*32 + k*4 + a];
    s *= (1.0f/(float)MM);
    Slds[wave*64 + lane] = s;
    S_ws[(size_t)bn*64 + lane] = s;
  }
  {
    const int p = lane >> 2, q = lane & 3;
    const float* Sw = &Slds[wave*64];
    float f = 0.f;
    #pragma unroll
    for (int a = 0; a < 4; ++a) f += Sw[p*4+a]*Sw[q*4+a];
    float fs = f, fss = f*f;
    for (int o = 32; o > 0; o >>= 1) { fs += __shfl_down(fs, o); fss += __shfl_down(fss, o); }
    if (lane == 0) { statp[bn*2+0] = fs; statp[bn*2+1] = fss; }
  }
}

/* ---- FUSED: MFMA MLP fwd+bwd + Chebyshev backward + scatter (this round) ----
   One block = 16 atoms. Forward MLP (round-8 k_mlp) -> dfeat kept in LDS
   (overlay dzb) -> dSb (overlay t0b) -> Eb (overlay h1b) -> scatter loop
   (round-0 k_bwdsc body, 8 pair-iters) with fpart overlaid on sl/xb/t0b.
   Removes: k_bwdsc launch + dependency drain, df_ws 4 MB round-trip,
   Sb/Db 4 MB re-read, dSb/Eb recompute. (256,2): grid is 512 = 2 blk/CU
   anyway -> generous 256-VGPR cap, zero spill risk (rounds 1/2/6 lesson). */
__global__ __launch_bounds__(256, 2) void k_fused(
    const float* __restrict__ S_ws, const int* __restrict__ tmap,
    const float* __restrict__ statp,
    const unsigned short* __restrict__ wtb, const unsigned short* __restrict__ wb,
    const float* __restrict__ b0, const float* __restrict__ b1,
    const float* __restrict__ b2, const float* __restrict__ Wout,
    const float* __restrict__ bout,
    const float* __restrict__ rvec, const int* __restrict__ nlist,
    const float* __restrict__ c_param,
    float* __restrict__ out)
{
  __shared__ float sm[SM_TOT];
  float* sl   = sm + SL_O;
  float* xb   = sm + XB_O;
  float* t0b  = sm + T0_O;
  float* h1b  = sm + H1_O;
  float* dzb  = sm + DZ_O;
  float* c_lds= sm + CL_O;
  float* es   = sm + ES_O;
  float* srd  = sm + SRD_O;
  float* muSd = sm + MU_O;
  float* wredc= sm + WR_O;
  float* vred = sm + VR_O;

  const int tb = blockIdx.x;
  const int bn0 = tb*MT;
  const int b = bn0 >> 10;
  const int n0l = bn0 & (NN-1);
  const int tid = threadIdx.x;
  const int wave = tid >> 6, lane = tid & 63;
  const int quad = lane >> 4, nI = lane & 15;
  const int t = tmap[n0l];
  c_lds[tid] = c_param[t*256 + tid];
  {
    const float4* src = (const float4*)(S_ws + (size_t)bn0*64);
    ((float4*)sl)[tid] = src[tid];
  }
  {
    float fs = 0.f, fss = 0.f;
    #pragma unroll 4
    for (int i = 0; i < 16; ++i) {
      const int e = i*256 + tid;
      const int bb = e >> 9;
      const int n = t*512 + (e & 511);
      const float2 v = *(const float2*)&statp[((size_t)(bb*NN + n))*2];
      fs += v.x; fss += v.y;
    }
    for (int o = 32; o > 0; o >>= 1) { fs += __shfl_down(fs, o); fss += __shfl_down(fss, o); }
    if ((tid & 63) == 0) { srd[(tid>>6)*2] = fs; srd[(tid>>6)*2+1] = fss; }
  }
  __syncthreads();
  if (tid == 0) {
    const float S1 = srd[0]+srd[2]+srd[4]+srd[6];
    const float S2 = srd[1]+srd[3]+srd[5]+srd[7];
    const float cnt = 512.0f * (float)BB * (float)NFEAT;
    const float mu = S1/cnt;
    const float var = (S2 - cnt*mu*mu)/(cnt - 1.0f);
    muSd[0] = mu; muSd[1] = sqrtf(fmaxf(var, 1e-20f));
  }
  __syncthreads();
  const float mu = muSd[0];
  const float inv_sd = 1.0f/muSd[1];
  #pragma unroll
  for (int i = 0; i < 4; ++i) {
    const int e = i*256 + tid;
    const int at = e >> 6, f = e & 63;
    const int p = f >> 2, q = f & 3;
    const float* Sr = &sl[at*64];
    float s = 0.f;
    #pragma unroll
    for (int a = 0; a < 4; ++a) s += Sr[p*4+a]*Sr[q*4+a];
    xb[at*AS0 + f] = (s - mu)*inv_sd;
  }
  __syncthreads();

  const int c0 = (wave*2+0)*16 + nI;
  const int c1 = (wave*2+1)*16 + nI;
  f4 acc0, acc1;

  /* L0 */
  acc0 = splat4(b0[t*HH + c0]);
  acc1 = splat4(b0[t*HH + c1]);
  {
    const unsigned short* B = wtb + WT0_OFF + t*8192;
    #pragma unroll
    for (int s = 0; s < 2; ++s) {
      const bf8 a  = a_frag(&xb[nI*AS0 + s*32 + quad*8]);
      const bf8 bA = *(const bf8*)&B[(size_t)c0*64 + s*32 + quad*8];
      const bf8 bB = *(const bf8*)&B[(size_t)c1*64 + s*32 + quad*8];
      acc0 = __builtin_amdgcn_mfma_f32_16x16x32_bf16(a, bA, acc0, 0, 0, 0);
      acc1 = __builtin_amdgcn_mfma_f32_16x16x32_bf16(a, bB, acc1, 0, 0, 0);
    }
  }
  #pragma unroll
  for (int r = 0; r < 4; ++r) {
    const int row = quad*4 + r;
    t0b[row*AS1 + c0] = ftanh(acc0[r]);
    t0b[row*AS1 + c1] = ftanh(acc1[r]);
  }
  __syncthreads();
  /* L1 */
  acc0 = splat4(b1[t*HH + c0]);
  acc1 = splat4(b1[t*HH + c1]);
  {
    const unsigned short* B = wtb + WT1_OFF + t*16384;
    #pragma unroll
    for (int s = 0; s < 4; ++s) {
      const bf8 a  = a_frag(&t0b[nI*AS1 + s*32 + quad*8]);
      const bf8 bA = *(const bf8*)&B[(size_t)c0*128 + s*32 + quad*8];
      const bf8 bB = *(const bf8*)&B[(size_t)c1*128 + s*32 + quad*8];
      acc0 = __builtin_amdgcn_mfma_f32_16x16x32_bf16(a, bA, acc0, 0, 0, 0);
      acc1 = __builtin_amdgcn_mfma_f32_16x16x32_bf16(a, bB, acc1, 0, 0, 0);
    }
  }
  #pragma unroll
  for (int r = 0; r < 4; ++r) {
    const int row = quad*4 + r;
    h1b[row*AS1 + c0] = ftanh(acc0[r]) + t0b[row*AS1 + c0];
    h1b[row*AS1 + c1] = ftanh(acc1[r]) + t0b[row*AS1 + c1];
  }
  __syncthreads();
  /* L2 */
  acc0 = splat4(b2[t*HH + c0]);
  acc1 = splat4(b2[t*HH + c1]);
  {
    const unsigned short* B = wtb + WT2_OFF + t*16384;
    #pragma unroll
    for (int s = 0; s < 4; ++s) {
      const bf8 a  = a_frag(&h1b[nI*AS1 + s*32 + quad*8]);
      const bf8 bA = *(const bf8*)&B[(size_t)c0*128 + s*32 + quad*8];
      const bf8 bB = *(const bf8*)&B[(size_t)c1*128 + s*32 + quad*8];
      acc0 = __builtin_amdgcn_mfma_f32_16x16x32_bf16(a, bA, acc0, 0, 0, 0);
      acc1 = __builtin_amdgcn_mfma_f32_16x16x32_bf16(a, bB, acc1, 0, 0, 0);
    }
  }
  #pragma unroll
  for (int r = 0; r < 4; ++r) {
    const int row = quad*4 + r;
    dzb[row*AS1 + c0] = acc0[r];
    dzb[row*AS1 + c1] = acc1[r];
  }
  __syncthreads();
  {
    const int at = tid >> 4, cb = (tid & 15)*8;
    const float* wop = Wout + t*HH;
    float ep = 0.f;
    #pragma unroll
    for (int j = 0; j < 8; ++j) {
      const int c = cb + j;
      const float z2 = dzb[at*AS1 + c];
      const float t2 = ftanh(z2);
      const float wo = wop[c];
      ep += (t2 + h1b[at*AS1 + c])*wo;
      dzb[at*AS1 + c] = wo*(1.0f - t2*t2);
    }
    ep += __shfl_down(ep, 8, 16);
    ep += __shfl_down(ep, 4, 16);
    ep += __shfl_down(ep, 2, 16);
    ep += __shfl_down(ep, 1, 16);
    if ((tid & 15) == 0) es[at] = ep;
  }
  __syncthreads();
  if (tid < MT) out[OUT_EI + bn0 + tid] = es[tid] + bout[t];
  if (tid == 0) {
    float s = 0.f;
    #pragma unroll
    for (int i = 0; i < MT; ++i) s += es[i];
    atomicAdd(&out[b], s + (float)MT*bout[t]);
  }

  /* BGEMM1: dh1 = wo + dz2 @ W2^T */
  {
    const float* wop = Wout + t*HH;
    acc0 = splat4(wop[c0]);
    acc1 = splat4(wop[c1]);
    const unsigned short* B = wb + WT2_OFF + t*16384;
    #pragma unroll
    for (int s = 0; s < 4; ++s) {
      const bf8 a  = a_frag(&dzb[nI*AS1 + s*32 + quad*8]);
      const bf8 bA = *(const bf8*)&B[(size_t)c0*128 + s*32 + quad*8];
      const bf8 bB = *(const bf8*)&B[(size_t)c1*128 + s*32 + quad*8];
      acc0 = __builtin_amdgcn_mfma_f32_16x16x32_bf16(a, bA, acc0, 0, 0, 0);
      acc1 = __builtin_amdgcn_mfma_f32_16x16x32_bf16(a, bB, acc1, 0, 0, 0);
    }
  }
  __syncthreads();
  float dh10[4], dh11[4];
  #pragma unroll
  for (int r = 0; r < 4; ++r) {
    const int row = quad*4 + r;
    dh10[r] = acc0[r]; dh11[r] = acc1[r];
    const float t1a = h1b[row*AS1 + c0] - t0b[row*AS1 + c0];
    const float t1b = h1b[row*AS1 + c1] - t0b[row*AS1 + c1];
    dzb[row*AS1 + c0] = acc0[r]*(1.0f - t1a*t1a);
    dzb[row*AS1 + c1] = acc1[r]*(1.0f - t1b*t1b);
  }
  __syncthreads();
  /* BGEMM2: dh0 = dh1 + dz1 @ W1^T */
  acc0[0]=dh10[0]; acc0[1]=dh10[1]; acc0[2]=dh10[2]; acc0[3]=dh10[3];
  acc1[0]=dh11[0]; acc1[1]=dh11[1]; acc1[2]=dh11[2]; acc1[3]=dh11[3];
  {
    const unsigned short* B = wb + WT1_OFF + t*16384;
    #pragma unroll
    for (int s = 0; s < 4; ++s) {
      const bf8 a  = a_frag(&dzb[nI*AS1 + s*32 + quad*8]);
      const bf8 bA = *(const bf8*)&B[(size_t)c0*128 + s*32 + quad*8];
      const bf8 bB = *(const bf8*)&B[(size_t)c1*128 + s*32 + quad*8];
      acc0 = __builtin_amdgcn_mfma_f32_16x16x32_bf16(a, bA, acc0, 0, 0, 0);
      acc1 = __builtin_amdgcn_mfma_f32_16x16x32_bf16(a, bB, acc1, 0, 0, 0);
    }
  }
  __syncthreads();
  #pragma unroll
  for (int r = 0; r < 4; ++r) {
    const int row = quad*4 + r;
    const float ta = t0b[row*AS1 + c0], tb2 = t0b[row*AS1 + c1];
    dzb[row*AS1 + c0] = acc0[r]*(1.0f - ta*ta);
    dzb[row*AS1 + c1] = acc1[r]*(1.0f - tb2*tb2);
  }
  __syncthreads();
  /* BGEMM3: dx = dz0 @ W0^T  (result stays in LDS as Db) */
  {
    const int cx = wave*16 + nI;
    acc0 = splat4(0.f);
    const unsigned short* B = wb + WT0_OFF + t*8192;
    #pragma unroll
    for (int s = 0; s < 4; ++s) {
      const bf8 a  = a_frag(&dzb[nI*AS1 + s*32 + quad*8]);
      const bf8 bA = *(const bf8*)&B[(size_t)cx*128 + s*32 + quad*8];
      acc0 = __builtin_amdgcn_mfma_f32_16x16x32_bf16(a, bA, acc0, 0, 0, 0);
    }
    __syncthreads();                 /* all dzb reads done -> safe to overlay */
    float* Db = dzb;                 /* dfeat, layout [at*64 + f] */
    #pragma unroll
    for (int r = 0; r < 4; ++r)
      Db[(quad*4 + r)*64 + cx] = acc0[r]*inv_sd;
  }
  __syncthreads();

  /* dSb (overlay t0b region): 1024 entries, 4 per thread */
  {
    float* dSb = t0b;
    const float* Db = dzb;
    #pragma unroll
    for (int it = 0; it < 4; ++it) {
      const int idx = it*256 + tid;
      const int at = idx >> 6, f = idx & 63;
      const int i = f >> 2, a = f & 3;
      const float* Sr = &sl[at*64];
      const float* Dr = &Db[at*64];
      float v = 0.f;
      #pragma unroll
      for (int q = 0; q < 4; ++q) v += Dr[i*4+q]*Sr[q*4+a];
      if (i < 4)
        for (int p = 0; p < 16; ++p) v += Dr[p*4+i]*Sr[p*4+a];
      dSb[idx] = v;
    }
  }
  __syncthreads();
  /* Eb (overlay h1b region) */
  {
    float* Eb = h1b;
    const float* dSb = t0b;
    #pragma unroll
    for (int it = 0; it < 4; ++it) {
      const int idx = it*256 + tid;
      const int at = idx >> 6, rem = idx & 63;
      const int tj = rem >> 5, a = (rem >> 3) & 3, k = rem & 7;
      float e = 0.f;
      #pragma unroll
      for (int p = 0; p < 16; ++p) e += dSb[at*64 + p*4 + a]*c_lds[tj*128 + p*8 + k];
      Eb[idx] = e;
    }
  }
  __syncthreads();
  /* zero fpart (overlays sl/xb/t0b: [0, 3264)) */
  {
    const float4 z4 = {0.f, 0.f, 0.f, 0.f};
    for (int i = tid; i < F3/4; i += 256) ((float4*)sm)[i] = z4;
  }
  __syncthreads();

  /* ---- scatter: round-0 body, 8 pair-iterations over 16 atoms ---- */
  float* fpart = sm;
  const float* Eb = h1b;
  float vir[9];
  #pragma unroll
  for (int i = 0; i < 9; ++i) vir[i] = 0.f;
  const int tjm = tid >> 7;
  const float dudr = 2.0f/SPANf;
  const float invM = 1.0f/(float)MM;

  const size_t rowbase = (size_t)bn0*MM;
  float px0, py0, pz0, px1, py1, pz1; int pnl0, pnl1;
  {
    const float* rp0 = rvec + (rowbase + tid)*3;
    const float* rp1 = rvec + (rowbase + MM + tid)*3;
    px0 = rp0[0]; py0 = rp0[1]; pz0 = rp0[2]; pnl0 = nlist[rowbase + tid];
    px1 = rp1[0]; py1 = rp1[1]; pz1 = rp1[2]; pnl1 = nlist[rowbase + MM + tid];
  }
  for (int a0 = 0; a0 < MT; a0 += 2) {
    const float x0 = px0, y0 = py0, z0 = pz0; const int nl0 = pnl0;
    const float x1 = px1, y1 = py1, z1 = pz1; const int nl1 = pnl1;
    if (a0 + 2 < MT) {
      const float* rp0 = rvec + (rowbase + (size_t)(a0+2)*MM + tid)*3;
      const float* rp1 = rvec + (rowbase + (size_t)(a0+3)*MM + tid)*3;
      px0 = rp0[0]; py0 = rp0[1]; pz0 = rp0[2];
      pnl0 = nlist[rowbase + (size_t)(a0+2)*MM + tid];
      px1 = rp1[0]; py1 = rp1[1]; pz1 = rp1[2];
      pnl1 = nlist[rowbase + (size_t)(a0+3)*MM + tid];
    }
    float Er0[32], Er1[32];
    {
      const float4* p0 = (const float4*)&Eb[a0*64 + tjm*32];
      const float4* p1 = (const float4*)&Eb[(a0+1)*64 + tjm*32];
      #pragma unroll
      for (int q = 0; q < 8; ++q) {
        const float4 v0 = p0[q], v1 = p1[q];
        Er0[q*4+0]=v0.x; Er0[q*4+1]=v0.y; Er0[q*4+2]=v0.z; Er0[q*4+3]=v0.w;
        Er1[q*4+0]=v1.x; Er1[q*4+1]=v1.y; Er1[q*4+2]=v1.z; Er1[q*4+3]=v1.w;
      }
    }
    const float r_0 = sqrtf(x0*x0 + y0*y0 + z0*z0);
    const float r_1 = sqrtf(x1*x1 + y1*y1 + z1*z1);
    const float ir0 = 1.0f/r_0, ir1 = 1.0f/r_1;
    const float ux0 = x0*ir0, uy0 = y0*ir0, uz0 = z0*ir0;
    const float ux1 = x1*ir1, uy1 = y1*ir1, uz1 = z1*ir1;
    float u0 = 2.0f*(r_0 - RMINf)/SPANf - 1.0f;
    float u1 = 2.0f*(r_1 - RMINf)/SPANf - 1.0f;
    u0 = fminf(fmaxf(u0, -1.0f), 1.0f);
    u1 = fminf(fmaxf(u1, -1.0f), 1.0f);
    float s0a, c0a, s1a, c1a;
    __sincosf(PIf*(r_0 - RMINf)/SPANf, &s0a, &c0a);
    __sincosf(PIf*(r_1 - RMINf)/SPANf, &s1a, &c1a);
    const float fc0 = 0.5f*(c0a + 1.0f), dfc0 = -0.5f*(PIf/SPANf)*s0a;
    const float fc1 = 0.5f*(c1a + 1.0f), dfc1 = -0.5f*(PIf/SPANf)*s1a;
    float ta0[4], tda0[4], ta1[4], tda1[4];
    #pragma unroll
    for (int aa = 0; aa < 4; ++aa) {
      ta0[aa]  = Er0[aa*8] + Er0[aa*8+1]*u0;
      tda0[aa] = Er0[aa*8+1];
      ta1[aa]  = Er1[aa*8] + Er1[aa*8+1]*u1;
      tda1[aa] = Er1[aa*8+1];
    }
    float t0m2 = 1.f, t0m1 = u0, d0m2 = 0.f, d0m1 = 1.f;
    float t1m2 = 1.f, t1m1 = u1, d1m2 = 0.f, d1m1 = 1.f;
    #pragma unroll
    for (int k = 2; k < BETA; ++k) {
      const float tk0 = 2.f*u0*t0m1 - t0m2;
      const float dk0 = 2.f*t0m1 + 2.f*u0*d0m1 - d0m2;
      const float tk1 = 2.f*u1*t1m1 - t1m2;
      const float dk1 = 2.f*t1m1 + 2.f*u1*d1m1 - d1m2;
      #pragma unroll
      for (int aa = 0; aa < 4; ++aa) {
        ta0[aa]  += Er0[aa*8+k]*tk0;
        tda0[aa] += Er0[aa*8+k]*dk0;
        ta1[aa]  += Er1[aa*8+k]*tk1;
        tda1[aa] += Er1[aa*8+k]*dk1;
      }
      t0m2 = t0m1; t0m1 = tk0; d0m2 = d0m1; d0m1 = dk0;
      t1m2 = t1m1; t1m1 = tk1; d1m2 = d1m1; d1m1 = dk1;
    }
    float A0 = dfc0*(ta0[0] + ux0*ta0[1] + uy0*ta0[2] + uz0*ta0[3])
             + fc0*dudr*(tda0[0] + ux0*tda0[1] + uy0*tda0[2] + uz0*tda0[3]);
    float A1 = dfc1*(ta1[0] + ux1*ta1[1] + uy1*ta1[2] + uz1*ta1[3])
             + fc1*dudr*(tda1[0] + ux1*tda1[1] + uy1*tda1[2] + uz1*tda1[3]);
    float q10 = fc0*ta0[1], q20 = fc0*ta0[2], q30 = fc0*ta0[3];
    float q11 = fc1*ta1[1], q21 = fc1*ta1[2], q31 = fc1*ta1[3];
    A0 *= invM; q10 *= invM; q20 *= invM; q30 *= invM;
    A1 *= invM; q11 *= invM; q21 *= invM; q31 *= invM;
    const float qu0 = q10*ux0 + q20*uy0 + q30*uz0;
    const float qu1 = q11*ux1 + q21*uy1 + q31*uz1;
    const float d00 = A0*ux0 + (q10 - qu0*ux0)*ir0;
    const float d01 = A0*uy0 + (q20 - qu0*uy0)*ir0;
    const float d02 = A0*uz0 + (q30 - qu0*uz0)*ir0;
    const float d10 = A1*ux1 + (q11 - qu1*ux1)*ir1;
    const float d11 = A1*uy1 + (q21 - qu1*uy1)*ir1;
    const float d12 = A1*uz1 + (q31 - qu1*uz1)*ir1;
    if (nl0 > 0) {
      const int j = nl0 - 1;
      atomicAdd(&fpart[j*3+0], -d00);
      atomicAdd(&fpart[j*3+1], -d01);
      atomicAdd(&fpart[j*3+2], -d02);
    }
    if (nl1 > 0) {
      const int j = nl1 - 1;
      atomicAdd(&fpart[j*3+0], -d10);
      atomicAdd(&fpart[j*3+1], -d11);
      atomicAdd(&fpart[j*3+2], -d12);
    }
    vir[0] -= x0*d00 + x1*d10; vir[1] -= x0*d01 + x1*d11; vir[2] -= x0*d02 + x1*d12;
    vir[3] -= y0*d00 + y1*d10; vir[4] -= y0*d01 + y1*d11; vir[5] -= y0*d02 + y1*d12;
    vir[6] -= z0*d00 + z1*d10; vir[7] -= z0*d01 + z1*d11; vir[8] -= z0*d02 + z1*d12;
    const float r00 = dpp_wave_sum(d00), r01 = dpp_wave_sum(d01), r02 = dpp_wave_sum(d02);
    const float r10 = dpp_wave_sum(d10), r11 = dpp_wave_sum(d11), r12 = dpp_wave_sum(d12);
    if (lane == 63) {
      wredc[(a0*4 + wave)*3 + 0] = r00;
      wredc[(a0*4 + wave)*3 + 1] = r01;
      wredc[(a0*4 + wave)*3 + 2] = r02;
      wredc[((a0+1)*4 + wave)*3 + 0] = r10;
      wredc[((a0+1)*4 + wave)*3 + 1] = r11;
      wredc[((a0+1)*4 + wave)*3 + 2] = r12;
    }
  }
  #pragma unroll
  for (int i = 0; i < 9; ++i) {
    const float v = dpp_wave_sum(vir[i]);
    if (lane == 63) vred[wave*9 + i] = v;
  }
  __syncthreads();
  if (tid < MT*3) {
    const int at = tid/3, c = tid - at*3;
    const float v = wredc[(at*4+0)*3+c] + wredc[(at*4+1)*3+c]
                  + wredc[(at*4+2)*3+c] + wredc[(at*4+3)*3+c];
    atomicAdd(&fpart[(n0l+at)*3 + c], v);
  }
  if (tid >= 64 && tid < 73) {
    const int i = tid - 64;
    atomicAdd(&out[OUT_VIR + b*9 + i],
              vred[i] + vred[9+i] + vred[18+i] + vred[27+i]);
  }
  __syncthreads();
  {
    float* dst = out + OUT_FORCE + (size_t)b*F3;
    for (int i = tid; i < F3; i += 256)
      atomicAdd(&dst[i], fpart[i]);
  }
}

extern "C" void kernel_launch(void* const* d_in, const int* in_sizes, int n_in,
                              void* d_out, int out_size, void* d_ws, size_t ws_size,
                              hipStream_t stream)
{
  const int*   nlist = (const int*)d_in[0];
  const int*   tmap  = (const int*)d_in[1];
  const float* rvec  = (const float*)d_in[2];
  const float* cpar  = (const float*)d_in[3];
  const float* W0 = (const float*)d_in[4];
  const float* b0 = (const float*)d_in[5];
  const float* W1 = (const float*)d_in[6];
  const float* b1 = (const float*)d_in[7];
  const float* W2 = (const float*)d_in[8];
  const float* b2 = (const float*)d_in[9];
  const float* Wout = (const float*)d_in[10];
  const float* bout = (const float*)d_in[11];
  float* out = (float*)d_out;
  float* ws = (float*)d_ws;
  float* S_ws   = ws + WS_S;
  float* statp  = ws + WS_STATP;
  unsigned short* wtb = (unsigned short*)(ws + WS_WTB);
  unsigned short* wb  = (unsigned short*)(ws + WS_WB);

  /* zero output: Etot/Force/Virial are atomic-accumulated */
  hipMemsetAsync(d_out, 0, (size_t)out_size, stream);

  k_feat <<<FEAT_BLKS + 640, 256, 0, stream>>>(rvec, tmap, cpar, S_ws, statp,
                                               W0, W1, W2, wtb, wb);
  k_fused<<<FUSE_BLKS, 256, 0, stream>>>(S_ws, tmap, statp, wtb, wb,
                                         b0, b1, b2, Wout, bout,
                                         rvec, nlist, cpar, out);
}